// Round 7
// baseline (960.610 us; speedup 1.0000x reference)
//
#include <hip/hip_runtime.h>
#include <cstdio>
#include <cmath>

typedef __attribute__((ext_vector_type(8))) short bf16x8;
typedef __attribute__((ext_vector_type(4))) float f32x4;

#define MFMA16(a, b, c) __builtin_amdgcn_mfma_f32_16x16x32_bf16((a), (b), (c), 0, 0, 0)

// ---------------- workspace layout (byte offsets) ----------------
#define WSO_PE    0u                          // float[128*128]
#define WSO_PWQS  65536u                      // bf16 packed [512][256]  (Wq@qp | sp)
#define WSO_PWK   (WSO_PWQS + 262144u)        // bf16 packed [256][512]  Wk@kp
#define WSO_PWV   (WSO_PWK + 262144u)         // bf16 packed [256][256]  Wv@vp
#define WSO_WOP   (WSO_PWV + 131072u)         // bf16 [256][256] row-major (k_wattn)
#define WSO_WC    (WSO_WOP + 131072u)         // bf16 conv fragment-packed
#define WSO_TB    (WSO_WC + 2359296u)         // f32 [6][128][256] PE tables
#define WSO_QH    (WSO_TB + 786432u)          // bf16 [2048][8][64][32]
#define WSO_KH    (WSO_QH + 67108864u)        // bf16 [2048][8][64][32]
#define WSO_VT    (WSO_KH + 67108864u)        // bf16 [2048][8][32][64]
#define WSO_YT    (WSO_VT + 67108864u)        // bf16 [8][16cc][128][128][32c]
#define WSO_SUMS  (WSO_YT + 134217728u)       // float[512]
#define WSO_SC    (WSO_SUMS + 2048u)          // float[512]
#define WSO_TOTAL (WSO_SC + 2048u)

#define SMEM_CONV 152064
#define SMEM_PROJ 65536

__device__ __forceinline__ unsigned short f2b(float x) {
  unsigned int u = __builtin_bit_cast(unsigned int, x);
  u += 0x7fffu + ((u >> 16) & 1u);
  return (unsigned short)(u >> 16);
}

__device__ __forceinline__ bf16x8 rd8(const unsigned short* s, int row, int stride, int k) {
  return *reinterpret_cast<const bf16x8*>(s + row * stride + (k ^ ((row & 7) << 3)));
}

// fragment-pack index for MFMA A operands: [kc][moG][rt][ks][lane][8]
__device__ __forceinline__ unsigned pack_idx(unsigned oc, unsigned ch, unsigned Mdiv) {
  unsigned kc = ch >> 6, moG = oc >> 6, rt = (oc >> 4) & 3, ks = (ch >> 5) & 1;
  unsigned l = (oc & 15) | (((ch >> 3) & 3) << 4), e = ch & 7;
  return ((((kc * Mdiv + moG) * 4 + rt) * 2 + ks) * 64 + l) * 8 + e;
}

// ================= prep: pe table + weight conversions =================
__global__ void k_prep(const float* __restrict__ spw, const float* __restrict__ opw,
                       const float* __restrict__ postw,
                       float* __restrict__ peT, unsigned short* __restrict__ pwqs,
                       unsigned short* __restrict__ wop, unsigned short* __restrict__ wc) {
  unsigned id = blockIdx.x * 256u + threadIdx.x;
  if (id < 16384u) {
    int p = id >> 7, j = id & 127;
    float div = expf(-9.210340371976184f * (float)(j & ~1) * (1.0f / 128.0f));
    float ang = (float)p * div;
    peT[id] = (j & 1) ? cosf(ang) : sinf(ang);
    return;
  }
  unsigned i = id - 16384u;
  if (i >= 1310720u) return;
  if (i < 65536u) {
    unsigned oc = i >> 8, ch = i & 255u;
    pwqs[pack_idx(oc + 256u, ch, 8u)] = f2b(spw[i]);
  } else if (i < 131072u) {
    wop[i - 65536u] = f2b(opw[i - 65536u]);
  } else {
    unsigned r = i - 131072u;
    unsigned e = r & 7u, l = (r >> 3) & 63u, rt = (r >> 9) & 3u;
    unsigned idx3 = r >> 11;
    unsigned tap = idx3 % 9u, q = idx3 / 9u;
    unsigned ocb = q & 3u, cc = q >> 2;
    unsigned oc = ocb * 64u + rt * 16u + (l & 15u);
    unsigned ic = cc * 32u + (l >> 4) * 8u + e;
    wc[r] = f2b(postw[(oc * 512u + ic) * 9u + tap]);
  }
}

// ================= fold: combined weights (packed) + PE tables =================
__global__ void k_fold(const float* __restrict__ qpw, const float* __restrict__ kpw,
                       const float* __restrict__ vpw, const float* __restrict__ inw,
                       const float* __restrict__ inb, const float* __restrict__ peT,
                       unsigned short* __restrict__ pwqs, unsigned short* __restrict__ pwk,
                       unsigned short* __restrict__ pwv, float* __restrict__ tb) {
  __shared__ float wrow[256];
  const int tid = threadIdx.x, bid = blockIdx.x;
  if (bid < 768) {
    int m = bid >> 8;                 // 0 q, 1 k, 2 v
    int e2 = bid & 255;
    wrow[tid] = inw[(m * 256 + e2) * 256 + tid];
    __syncthreads();
    if (m == 1) {
      float a0 = 0.f, a1 = 0.f;
      for (int e = 0; e < 256; ++e) {
        float s = wrow[e];
        a0 = fmaf(s, kpw[e * 512 + tid], a0);
        a1 = fmaf(s, kpw[e * 512 + 256 + tid], a1);
      }
      pwk[pack_idx(e2, tid, 4u)] = f2b(a0);
      pwk[pack_idx(e2, tid + 256, 4u)] = f2b(a1);
    } else {
      const float* pw = (m == 0) ? qpw : vpw;
      float a0 = 0.f;
      for (int e = 0; e < 256; ++e) a0 = fmaf(wrow[e], pw[e * 256 + tid], a0);
      if (m == 0) pwqs[pack_idx(e2, tid, 8u)] = f2b(a0);
      else        pwv[pack_idx(e2, tid, 4u)] = f2b(a0);
    }
  } else {
    int r = bid - 768;
    int t = r >> 7, p = r & 127;      // t: 0 Aq,1 Bq,2 Ak,3 Bk,4 Av,5 Bv
    if (tid < 128) wrow[tid] = peT[p * 128 + tid];
    __syncthreads();
    int woff = (t >> 1) * 256, joff = (t & 1) * 128;
    float acc = (t & 1) ? 0.f : inb[woff + tid];
    const float* wr = inw + (size_t)(woff + tid) * 256 + joff;
    for (int j = 0; j < 128; ++j) acc = fmaf(wrow[j], wr[j], acc);
    tb[t * 32768 + p * 256 + tid] = acc;
  }
}

// ================= shared GEMM (k_wattn): OUT[e][tok] += W[e][c] * X[tok][c] ===========
__device__ __forceinline__ void gemm4x4(f32x4 acc[4][4], const unsigned short* __restrict__ wA,
                                        int Kw, int kw0, const unsigned short* sB, int strideB,
                                        int nK, int wid, int lane) {
  const int rA = lane & 15;
  const int kq = (lane >> 4) << 3;
  for (int ks = 0; ks < nK; ks += 32) {
    bf16x8 a[4];
#pragma unroll
    for (int rt = 0; rt < 4; ++rt)
      a[rt] = *reinterpret_cast<const bf16x8*>(wA + (wid * 64 + rt * 16 + rA) * Kw + kw0 + ks + kq);
#pragma unroll
    for (int ct = 0; ct < 4; ++ct) {
      bf16x8 bb = rd8(sB, ct * 16 + rA, strideB, ks + kq);
#pragma unroll
      for (int rt = 0; rt < 4; ++rt) acc[rt][ct] = MFMA16(a[rt], bb, acc[rt][ct]);
    }
  }
}

// y_t layout: [b][cc=ch/32][h][w][ch%32]
__device__ __forceinline__ void epi_global(unsigned short* __restrict__ y_t, const f32x4 acc[4][4],
                                           const float* __restrict__ bias, int chOff,
                                           int b, int h0, int w0, int wid, int lane) {
#pragma unroll
  for (int rt = 0; rt < 4; ++rt) {
    int e0 = wid * 64 + rt * 16 + ((lane >> 4) << 2);
    float4 bs = bias ? *reinterpret_cast<const float4*>(bias + e0) : make_float4(0.f, 0.f, 0.f, 0.f);
    int ch = chOff + e0;
#pragma unroll
    for (int ct = 0; ct < 4; ++ct) {
      int tok = ct * 16 + (lane & 15);
      int r = tok >> 3, cpx = tok & 7;
      long gy = ((((long)(b * 16 + (ch >> 5)) * 128 + (h0 + r)) * 128 + (w0 + cpx)) << 5) + (ch & 31);
      ushort4 pk;
      pk.x = f2b(acc[rt][ct][0] + bs.x);
      pk.y = f2b(acc[rt][ct][1] + bs.y);
      pk.z = f2b(acc[rt][ct][2] + bs.z);
      pk.w = f2b(acc[rt][ct][3] + bs.w);
      *reinterpret_cast<ushort4*>(y_t + gy) = pk;
    }
  }
}

// ================= projections v2: strip-tile GEMM, one pass per block =================
// block = 1024 thr / 16 waves; tile = 256 tok (8h x 32w strip = 4 windows) x 256 oc
// wave = 64 oc x 64 tok (one window); sib: 0=q 1=skip 2=k 3=v
// launch_bounds(1024, 1): 4 waves/SIMD block-fit -> 128 VGPR cap (64 spills ~55 regs)
__launch_bounds__(1024, 1)
__global__ void k_proj(const float* __restrict__ x5, const float* __restrict__ d1,
                       const float* __restrict__ d2,
                       const unsigned short* __restrict__ pwqs, const unsigned short* __restrict__ pwk,
                       const unsigned short* __restrict__ pwv, const float* __restrict__ tb,
                       unsigned short* __restrict__ qh, unsigned short* __restrict__ kh,
                       unsigned short* __restrict__ vt, unsigned short* __restrict__ y_t) {
  extern __shared__ unsigned short sB[];   // 2 x 16384 shorts ([256tok][64ch] swizzled)
  const int tid = threadIdx.x, l = tid & 63, wv = tid >> 6;
  const int l15 = l & 15, gq = l >> 4;
  const int braw = blockIdx.x;
  const int bid = (braw & 7) * 256 + (braw >> 3);      // XCD-grouped siblings
  const int sib = bid & 3, tile = bid >> 2;
  const int wq = tile & 3, hs = (tile >> 2) & 15, b = tile >> 6;
  const int h0 = hs * 8, w0 = wq * 32;
  const int win = wv & 3, mo = wv >> 2;                // 4 win x 4 mo waves

  const float* src; const unsigned short* wf; int Cin, nkc, Mdiv, moG;
  if (sib == 0)      { src = d1; wf = pwqs; Cin = 256; nkc = 4; Mdiv = 8; moG = mo; }
  else if (sib == 1) { src = d1; wf = pwqs; Cin = 256; nkc = 4; Mdiv = 8; moG = 4 + mo; }
  else if (sib == 2) { src = x5; wf = pwk;  Cin = 512; nkc = 8; Mdiv = 4; moG = mo; }
  else               { src = d2; wf = pwv;  Cin = 256; nkc = 4; Mdiv = 4; moG = mo; }

  // staging mapping: lane -> (q = float4-col, rbit, cq); wave -> (c-base, r-base)
  const int sq = l & 7, rbit = (l >> 3) & 1, cq = l >> 4;
  const long srcb = ((long)(b * Cin) << 14) + (long)h0 * 128 + w0 + sq * 4;

  // B-frag LDS byte-offset bases (per ct); swizzle s = (tok ^ tok>>2) & 7
  int bOff[4];
#pragma unroll
  for (int ct = 0; ct < 4; ++ct) {
    int wtok = ct * 16 + l15;
    int tok = (wtok >> 3) * 32 + win * 8 + (wtok & 7);
    int s = (tok ^ (tok >> 2)) & 7;
    bOff[ct] = (tok << 6) + ((gq ^ s) << 3);
  }

  const f32x4 vz = {0.f, 0.f, 0.f, 0.f};
  f32x4 acc[4][4];
#pragma unroll
  for (int rt = 0; rt < 4; ++rt)
#pragma unroll
    for (int ct = 0; ct < 4; ++ct) acc[rt][ct] = vz;

  float4 pv[4];
  auto stage = [&](int kc) {
#pragma unroll
    for (int i = 0; i < 4; ++i) {
      int c = ((wv & 7) << 3) + (cq << 1) + (i & 1);
      int r = ((wv >> 3) << 2) + ((i >> 1) << 1) + rbit;
      pv[i] = *reinterpret_cast<const float4*>(src + srcb + ((long)(kc * 64 + c) << 14) + r * 128);
    }
  };
  auto wrt = [&](unsigned short* buf) {
#pragma unroll
    for (int i = 0; i < 4; ++i) {
      int c = ((wv & 7) << 3) + (cq << 1) + (i & 1);
      int r = ((wv >> 3) << 2) + ((i >> 1) << 1) + rbit;
      int tok0 = (r << 5) + (sq << 2);
      const float* f = reinterpret_cast<const float*>(&pv[i]);
#pragma unroll
      for (int e = 0; e < 4; ++e) {
        int tok = tok0 + e;
        int s = (tok ^ (tok >> 2)) & 7;
        buf[(tok << 6) + ((((c >> 3) ^ s) << 3) | (c & 7))] = f2b(f[e]);
      }
    }
  };

  stage(0);
  wrt(sB);
  __syncthreads();

#pragma unroll 1
  for (int kc = 0; kc < nkc; ++kc) {
    unsigned short* buf = sB + ((kc & 1) << 14);
    if (kc + 1 < nkc) stage(kc + 1);                     // issue early (T14)
    const unsigned short* pa = wf + (((kc * Mdiv + moG) << 12) | (l << 3));
#pragma unroll
    for (int ksi = 0; ksi < 2; ++ksi) {
      bf16x8 a[4];
#pragma unroll
      for (int rt = 0; rt < 4; ++rt)
        a[rt] = *reinterpret_cast<const bf16x8*>(pa + ((rt * 2 + ksi) << 9));
#pragma unroll
      for (int ct = 0; ct < 4; ++ct) {
        bf16x8 bb = *reinterpret_cast<const bf16x8*>(buf + (bOff[ct] ^ (ksi << 5)));
#pragma unroll
        for (int rt = 0; rt < 4; ++rt) acc[rt][ct] = MFMA16(a[rt], bb, acc[rt][ct]);
      }
    }
    if (kc + 1 < nkc) wrt(sB + (((kc + 1) & 1) << 14));  // write late (T14)
    __syncthreads();
  }

  // ---- epilogues ----
  const int win_g = ((b * 16 + hs) << 4) + (wq << 2) + win;
  if (sib == 0 || sib == 2) {
    const float* At = tb + (sib == 0 ? 0 : 65536);
    const float* Bt = tb + (sib == 0 ? 32768 : 98304);
    unsigned short* dst = (sib == 0 ? qh : kh) + ((size_t)win_g << 14);
#pragma unroll
    for (int rt = 0; rt < 4; ++rt) {
      int oc = mo * 64 + rt * 16 + gq * 4;
#pragma unroll
      for (int ct = 0; ct < 4; ++ct) {
        int wtok = ct * 16 + l15;
        int h = h0 + (wtok >> 3), wgl = w0 + win * 8 + (wtok & 7);
        float4 av = *reinterpret_cast<const float4*>(At + h * 256 + oc);
        float4 bv = *reinterpret_cast<const float4*>(Bt + wgl * 256 + oc);
        ushort4 pk;
        pk.x = f2b(acc[rt][ct][0] + av.x + bv.x);
        pk.y = f2b(acc[rt][ct][1] + av.y + bv.y);
        pk.z = f2b(acc[rt][ct][2] + av.z + bv.z);
        pk.w = f2b(acc[rt][ct][3] + av.w + bv.w);
        *reinterpret_cast<ushort4*>(dst + ((oc >> 5) << 11) + (wtok << 5) + (oc & 31)) = pk;
      }
    }
  } else if (sib == 1) {
#pragma unroll
    for (int rt = 0; rt < 4; ++rt) {
      int ch = 256 + mo * 64 + rt * 16 + gq * 4;
      int cc = ch >> 5;
#pragma unroll
      for (int ct = 0; ct < 4; ++ct) {
        int wtok = ct * 16 + l15;
        int h = h0 + (wtok >> 3), wgl = w0 + win * 8 + (wtok & 7);
        long gy = ((((long)(b * 16 + cc) * 128 + h) * 128 + wgl) << 5) + (ch & 31);
        ushort4 pk;
        pk.x = f2b(acc[rt][ct][0]);
        pk.y = f2b(acc[rt][ct][1]);
        pk.z = f2b(acc[rt][ct][2]);
        pk.w = f2b(acc[rt][ct][3]);
        *reinterpret_cast<ushort4*>(y_t + gy) = pk;
      }
    }
  } else {
    const float* At = tb + 131072;
    const float* Bt = tb + 163840;
    unsigned short* dst = vt + ((size_t)win_g << 14);
#pragma unroll
    for (int rt = 0; rt < 4; ++rt) {
      int oc = mo * 64 + rt * 16 + gq * 4;
      int hd = oc >> 5, chb = oc & 31;
#pragma unroll
      for (int ct = 0; ct < 4; ++ct) {
        int wtok = ct * 16 + l15;
        int h = h0 + (wtok >> 3), wgl = w0 + win * 8 + (wtok & 7);
        float4 av = *reinterpret_cast<const float4*>(At + h * 256 + oc);
        float4 bv = *reinterpret_cast<const float4*>(Bt + wgl * 256 + oc);
        const float* avf = reinterpret_cast<const float*>(&av);
        const float* bvf = reinterpret_cast<const float*>(&bv);
#pragma unroll
        for (int j = 0; j < 4; ++j)
          dst[(hd << 11) + (chb + j) * 64 + wtok] = f2b(acc[rt][ct][j] + avf[j] + bvf[j]);
      }
    }
  }
}

// ================= window attention + out-proj (unchanged) =================
__launch_bounds__(256, 3)
__global__ void k_wattn(const unsigned short* __restrict__ qh, const unsigned short* __restrict__ kh,
                        const unsigned short* __restrict__ vt, const unsigned short* __restrict__ wop,
                        const float* __restrict__ out_b, unsigned short* __restrict__ y_t) {
  __shared__ unsigned short Pb[4096];
  __shared__ unsigned short bufO[16384];
  const int tid = threadIdx.x, lane = tid & 63, wid = tid >> 6;
  const int gq = lane >> 4, l15 = lane & 15, kq = gq << 3;
  const int bid = blockIdx.x;
  const int win = ((bid & 7) << 8) | (bid >> 3);
  const int b = win >> 8, wh = (win >> 4) & 15, ww = win & 15;
  const int h0 = wh * 8, w0 = ww * 8;

  const unsigned short* qw = qh + ((size_t)win << 14);
  const unsigned short* kw = kh + ((size_t)win << 14);
  const unsigned short* vw = vt + ((size_t)win << 14);

  const f32x4 vz = {0.f, 0.f, 0.f, 0.f};
  const float scl = 0.17677669529663687f;
  f32x4 o0[8], o1[8];
#pragma unroll
  for (int h = 0; h < 8; ++h) { o0[h] = vz; o1[h] = vz; }

#pragma unroll
  for (int hd = 0; hd < 8; ++hd) {
    const unsigned short* qb = qw + (hd << 11);
    const unsigned short* kb = kw + (hd << 11);
    const unsigned short* vb = vw + (hd << 11);
    bf16x8 aq = *reinterpret_cast<const bf16x8*>(qb + ((wid * 16 + l15) << 5) + kq);
    f32x4 sv[4];
#pragma unroll
    for (int ct = 0; ct < 4; ++ct) {
      bf16x8 bk = *reinterpret_cast<const bf16x8*>(kb + ((ct * 16 + l15) << 5) + kq);
      sv[ct] = MFMA16(aq, bk, vz);
    }
    float pr[4][4];
#pragma unroll
    for (int j = 0; j < 4; ++j) {
      float mx = fmaxf(fmaxf(sv[0][j], sv[1][j]), fmaxf(sv[2][j], sv[3][j])) * scl;
#pragma unroll
      for (int m = 8; m >= 1; m >>= 1) mx = fmaxf(mx, __shfl_xor(mx, m));
      float sum = 0.f;
#pragma unroll
      for (int ct = 0; ct < 4; ++ct) {
        float p = __expf(sv[ct][j] * scl - mx);
        pr[ct][j] = p;
        sum += p;
      }
#pragma unroll
      for (int m = 8; m >= 1; m >>= 1) sum += __shfl_xor(sum, m);
      float inv = 1.f / sum;
#pragma unroll
      for (int ct = 0; ct < 4; ++ct) pr[ct][j] *= inv;
    }
#pragma unroll
    for (int ct = 0; ct < 4; ++ct)
#pragma unroll
      for (int j = 0; j < 4; ++j) {
        int q = wid * 16 + gq * 4 + j;
        int kt = ct * 16 + l15;
        Pb[q * 64 + (kt ^ ((q & 7) << 3))] = f2b(pr[ct][j]);
      }
#pragma unroll
    for (int ks = 0; ks < 64; ks += 32) {
      bf16x8 bp = rd8(Pb, wid * 16 + l15, 64, ks + kq);
      bf16x8 a0 = *reinterpret_cast<const bf16x8*>(vb + (l15 << 6) + ks + kq);
      bf16x8 a1 = *reinterpret_cast<const bf16x8*>(vb + ((16 + l15) << 6) + ks + kq);
      o0[hd] = MFMA16(a0, bp, o0[hd]);
      o1[hd] = MFMA16(a1, bp, o1[hd]);
    }
  }

  {
    int tok = wid * 16 + l15;
    int sw = (tok & 7) << 3;
#pragma unroll
    for (int hd = 0; hd < 8; ++hd)
#pragma unroll
      for (int rt = 0; rt < 2; ++rt) {
        f32x4 ov = rt ? o1[hd] : o0[hd];
        int ch0 = hd * 32 + rt * 16 + gq * 4;
        ushort4 pk;
        pk.x = f2b(ov[0]); pk.y = f2b(ov[1]); pk.z = f2b(ov[2]); pk.w = f2b(ov[3]);
        *reinterpret_cast<ushort4*>(&bufO[tok * 256 + (ch0 ^ sw)]) = pk;
      }
  }
  __syncthreads();

  f32x4 accA[4][4];
#pragma unroll
  for (int i = 0; i < 4; ++i)
#pragma unroll
    for (int j = 0; j < 4; ++j) accA[i][j] = vz;
  gemm4x4(accA, wop, 256, 0, bufO, 256, 256, wid, lane);
  epi_global(y_t, accA, out_b, 0, b, h0, w0, wid, lane);
}

// ================= conv 3x3 (512->256) implicit GEMM (unchanged) =================
__device__ __forceinline__ void patch_load(const unsigned short* __restrict__ y_t,
                                           int b, int cc, int h0, int w0, int tid, uint4* pv) {
#pragma unroll
  for (int k = 0; k < 5; ++k) {
    int s = tid + (k << 9);
    uint4 v = make_uint4(0u, 0u, 0u, 0u);
    if (s < 2448) {
      int pr = (s * 482) >> 16;
      int rem = s - pr * 136;
      int pcpx = rem >> 2, g = rem & 3;
      int hh = h0 + pr - 1, wp = w0 + pcpx - 1;
      if ((unsigned)hh < 128u && (unsigned)wp < 128u)
        v = *reinterpret_cast<const uint4*>(
            y_t + ((((long)(b * 16 + cc) * 128 + hh) * 128 + wp) << 5) + (g << 3));
    }
    pv[k] = v;
  }
}

__device__ __forceinline__ void patch_store(unsigned short* buf, int tid, const uint4* pv) {
#pragma unroll
  for (int k = 0; k < 5; ++k) {
    int s = tid + (k << 9);
    if (s < 2448) {
      int pr = (s * 482) >> 16;
      int rem = s - pr * 136;
      int pcpx = rem >> 2, g = rem & 3;
      int pidx = pr * 34 + pcpx;
      *reinterpret_cast<uint4*>(buf + (pidx << 5) + ((g ^ ((pidx >> 1) & 3)) << 3)) = pv[k];
    }
  }
}

__device__ __forceinline__ void stage_A(const unsigned short* __restrict__ wA, int cc, int ocb,
                                        unsigned short* dstBase, int tid) {
  const unsigned short* src = wA + (size_t)(cc * 4 + ocb) * 18432 + tid * 8;
  unsigned short* dst = dstBase + tid * 8;
#pragma unroll
  for (int k = 0; k < 4; ++k) {
    __builtin_amdgcn_global_load_lds(
        (const __attribute__((address_space(1))) unsigned int*)(src + k * 4096),
        (__attribute__((address_space(3))) unsigned int*)(dst + k * 4096), 16, 0, 0);
  }
  if (tid < 256)
    __builtin_amdgcn_global_load_lds(
        (const __attribute__((address_space(1))) unsigned int*)(src + 16384),
        (__attribute__((address_space(3))) unsigned int*)(dst + 16384), 16, 0, 0);
}

__launch_bounds__(512, 2)
__global__ void k_conv(const unsigned short* __restrict__ y_t, const unsigned short* __restrict__ wc,
                       float* __restrict__ out) {
  extern __shared__ unsigned short cs[];
  unsigned short* Pb0 = cs;
  unsigned short* Pb1 = cs + 19584;
  unsigned short* Ab0 = cs + 39168;
  unsigned short* Ab1 = cs + 57600;

  const int tid = threadIdx.x, lane = tid & 63, pxg = tid >> 6;
  const int gq = lane >> 4, l15 = lane & 15;
  const int bi = ((int)blockIdx.x & 7) * 128 + ((int)blockIdx.x >> 3);
  const int ocb = bi & 3, wb = (bi >> 2) & 3, hb = (bi >> 4) & 7, b = bi >> 7;
  const int h0 = hb * 16, w0 = wb * 32;

  const f32x4 vz = {0.f, 0.f, 0.f, 0.f};
  f32x4 acc[4][4];
#pragma unroll
  for (int rt = 0; rt < 4; ++rt)
#pragma unroll
    for (int ct = 0; ct < 4; ++ct) acc[rt][ct] = vz;

  uint4 pv[5];
  patch_load(y_t, b, 0, h0, w0, tid, pv);
  stage_A(wc, 0, ocb, Ab0, tid);
  patch_store(Pb0, tid, pv);
  __syncthreads();

#pragma unroll 1
  for (int cc = 0; cc < 16; ++cc) {
    const unsigned short* pb = (cc & 1) ? Pb1 : Pb0;
    const unsigned short* pa = (cc & 1) ? Ab1 : Ab0;
    if (cc < 15) {
      patch_load(y_t, b, cc + 1, h0, w0, tid, pv);
      stage_A(wc, cc + 1, ocb, (cc & 1) ? Ab0 : Ab1, tid);
    }

#pragma unroll
    for (int kx = 0; kx < 3; ++kx) {
      bf16x8 bfr[4][2];
#pragma unroll
      for (int r = 0; r < 4; ++r)
#pragma unroll
        for (int ws = 0; ws < 2; ++ws) {
          int pidx = (pxg * 2 + r) * 34 + ws * 16 + l15 + kx;
          bfr[r][ws] = *reinterpret_cast<const bf16x8*>(
              pb + (pidx << 5) + ((gq ^ ((pidx >> 1) & 3)) << 3));
        }
      bf16x8 afr[3][4];
#pragma unroll
      for (int ky = 0; ky < 3; ++ky)
#pragma unroll
        for (int rt = 0; rt < 4; ++rt)
          afr[ky][rt] = *reinterpret_cast<const bf16x8*>(
              pa + (((ky * 3 + kx) * 4 + rt) << 9) + lane * 8);
#pragma unroll
      for (int ky = 0; ky < 3; ++ky)
#pragma unroll
        for (int ct = 0; ct < 4; ++ct) {
          int r = (ct >> 1) + ky, ws = ct & 1;
#pragma unroll
          for (int rt = 0; rt < 4; ++rt)
            acc[rt][ct] = MFMA16(afr[ky][rt], bfr[r][ws], acc[rt][ct]);
        }
    }

    if (cc < 15) patch_store((cc & 1) ? Pb0 : Pb1, tid, pv);
    __syncthreads();
  }

#pragma unroll
  for (int rt = 0; rt < 4; ++rt) {
    int oc0 = ocb * 64 + rt * 16 + gq * 4;
#pragma unroll
    for (int ct = 0; ct < 4; ++ct) {
      int hh = h0 + pxg * 2 + (ct >> 1), wp = w0 + ((ct & 1) << 4) + l15;
      long base = (((long)(b * 256 + oc0)) * 128 + hh) * 128 + wp;
#pragma unroll
      for (int j = 0; j < 4; ++j) out[base + (long)j * 16384] = acc[rt][ct][j];
    }
  }
}

// ================= BN stats / finalize / apply =================
__global__ void k_stats(const float* __restrict__ out, float* __restrict__ sums) {
  __shared__ float s1[256], s2[256];
  int c = blockIdx.x, tid = threadIdx.x;
  float a1 = 0.f, a2 = 0.f;
  for (int bb = 0; bb < 8; ++bb) {
    const float4* p = reinterpret_cast<const float4*>(out + ((long)(bb * 256 + c)) * 16384);
    for (int i = tid; i < 4096; i += 256) {
      float4 v = p[i];
      a1 += v.x + v.y + v.z + v.w;
      a2 += v.x * v.x + v.y * v.y + v.z * v.z + v.w * v.w;
    }
  }
  s1[tid] = a1; s2[tid] = a2;
  __syncthreads();
  for (int s = 128; s > 0; s >>= 1) {
    if (tid < s) { s1[tid] += s1[tid + s]; s2[tid] += s2[tid + s]; }
    __syncthreads();
  }
  if (tid == 0) { sums[c] = s1[0]; sums[256 + c] = s2[0]; }
}

__global__ void k_final(const float* __restrict__ sums, const float* __restrict__ gamma,
                        const float* __restrict__ beta, float* __restrict__ sc) {
  int c = threadIdx.x;
  float mean = sums[c] * (1.f / 131072.f);
  float var = sums[256 + c] * (1.f / 131072.f) - mean * mean;
  float s = gamma[c] * rsqrtf(var + 1e-5f);
  sc[c] = s;
  sc[256 + c] = beta[c] - mean * s;
}

__global__ void k_apply(float* __restrict__ out, const float* __restrict__ sc) {
  const long n4 = 33554432 / 4;
  for (long i4 = (long)blockIdx.x * 256 + threadIdx.x; i4 < n4; i4 += (long)gridDim.x * 256) {
    float4 v = reinterpret_cast<float4*>(out)[i4];
    int c = (int)((i4 >> 12) & 255);
    float s = sc[c], sh = sc[256 + c];
    v.x = fmaxf(v.x * s + sh, 0.f);
    v.y = fmaxf(v.y * s + sh, 0.f);
    v.z = fmaxf(v.z * s + sh, 0.f);
    v.w = fmaxf(v.w * s + sh, 0.f);
    reinterpret_cast<float4*>(out)[i4] = v;
  }
}

// ================= launch =================
extern "C" void kernel_launch(void* const* d_in, const int* in_sizes, int n_in,
                              void* d_out, int out_size, void* d_ws, size_t ws_size,
                              hipStream_t stream) {
  const float* x5 = (const float*)d_in[0];
  const float* d1 = (const float*)d_in[1];
  const float* d2 = (const float*)d_in[2];
  const float* kp = (const float*)d_in[3];
  const float* qp = (const float*)d_in[4];
  const float* vp = (const float*)d_in[5];
  const float* spw = (const float*)d_in[6];
  const float* inw = (const float*)d_in[7];
  const float* inb = (const float*)d_in[8];
  const float* opw = (const float*)d_in[9];
  const float* opb = (const float*)d_in[10];
  const float* pw = (const float*)d_in[11];
  const float* gamma = (const float*)d_in[12];
  const float* beta = (const float*)d_in[13];

  if (ws_size < (size_t)WSO_TOTAL) {
    fprintf(stderr, "kernel_launch: ws too small: %zu < %u\n", ws_size, WSO_TOTAL);
    return;
  }

  char* ws = (char*)d_ws;
  float* peT = (float*)(ws + WSO_PE);
  unsigned short* pwqs = (unsigned short*)(ws + WSO_PWQS);
  unsigned short* pwk = (unsigned short*)(ws + WSO_PWK);
  unsigned short* pwv = (unsigned short*)(ws + WSO_PWV);
  unsigned short* w_op = (unsigned short*)(ws + WSO_WOP);
  unsigned short* w_c = (unsigned short*)(ws + WSO_WC);
  float* tb = (float*)(ws + WSO_TB);
  unsigned short* qh = (unsigned short*)(ws + WSO_QH);
  unsigned short* kh = (unsigned short*)(ws + WSO_KH);
  unsigned short* vt = (unsigned short*)(ws + WSO_VT);
  unsigned short* y_t = (unsigned short*)(ws + WSO_YT);
  float* sums = (float*)(ws + WSO_SUMS);
  float* sc = (float*)(ws + WSO_SC);

  hipFuncSetAttribute(reinterpret_cast<const void*>(k_conv),
                      hipFuncAttributeMaxDynamicSharedMemorySize, SMEM_CONV);
  hipFuncSetAttribute(reinterpret_cast<const void*>(k_proj),
                      hipFuncAttributeMaxDynamicSharedMemorySize, SMEM_PROJ);

  k_prep<<<5184, 256, 0, stream>>>(spw, opw, pw, peT, pwqs, w_op, w_c);
  k_fold<<<1536, 256, 0, stream>>>(qp, kp, vp, inw, inb, peT, pwqs, pwk, pwv, tb);
  k_proj<<<2048, 1024, SMEM_PROJ, stream>>>(x5, d1, d2, pwqs, pwk, pwv, tb, qh, kh, vt, y_t);
  k_wattn<<<2048, 256, 0, stream>>>(qh, kh, vt, w_op, opb, y_t);
  k_conv<<<1024, 512, SMEM_CONV, stream>>>(y_t, w_c, (float*)d_out);
  k_stats<<<256, 256, 0, stream>>>((const float*)d_out, sums);
  k_final<<<1, 256, 0, stream>>>(sums, gamma, beta, sc);
  k_apply<<<2048, 256, 0, stream>>>((float*)d_out, sc);
}

// Round 8
// 794.494 us; speedup vs baseline: 1.2091x; 1.2091x over previous
//
#include <hip/hip_runtime.h>
#include <cstdio>
#include <cmath>

typedef __attribute__((ext_vector_type(8))) short bf16x8;
typedef __attribute__((ext_vector_type(4))) float f32x4;

#define MFMA16(a, b, c) __builtin_amdgcn_mfma_f32_16x16x32_bf16((a), (b), (c), 0, 0, 0)

// ---------------- workspace layout (byte offsets) ----------------
#define WSO_PE    0u                          // float[128*128]
#define WSO_PWQS  65536u                      // bf16 packed [512][256]  (Wq@qp | sp)
#define WSO_PWK   (WSO_PWQS + 262144u)        // bf16 packed [256][512]  Wk@kp
#define WSO_PWV   (WSO_PWK + 262144u)         // bf16 packed [256][256]  Wv@vp
#define WSO_WOP   (WSO_PWV + 131072u)         // bf16 [256][256] row-major (k_wattn)
#define WSO_WC    (WSO_WOP + 131072u)         // bf16 conv fragment-packed
#define WSO_TB    (WSO_WC + 2359296u)         // f32 [6][128][256] PE tables
#define WSO_QH    (WSO_TB + 786432u)          // bf16 [2048][8][64][32]
#define WSO_KH    (WSO_QH + 67108864u)        // bf16 [2048][8][64][32]
#define WSO_VT    (WSO_KH + 67108864u)        // bf16 [2048][8][32][64]
#define WSO_YT    (WSO_VT + 67108864u)        // bf16 [8][16cc][128][128][32c]
#define WSO_SUMS  (WSO_YT + 134217728u)       // float[512]
#define WSO_SC    (WSO_SUMS + 2048u)          // float[512]
#define WSO_TOTAL (WSO_SC + 2048u)

#define SMEM_CONV 152064

__device__ __forceinline__ unsigned short f2b(float x) {
  unsigned int u = __builtin_bit_cast(unsigned int, x);
  u += 0x7fffu + ((u >> 16) & 1u);
  return (unsigned short)(u >> 16);
}

__device__ __forceinline__ bf16x8 rd8(const unsigned short* s, int row, int stride, int k) {
  return *reinterpret_cast<const bf16x8*>(s + row * stride + (k ^ ((row & 7) << 3)));
}

// fragment-pack index for MFMA A operands: [kc][moG][rt][ks][lane][8]
__device__ __forceinline__ unsigned pack_idx(unsigned oc, unsigned ch, unsigned Mdiv) {
  unsigned kc = ch >> 6, moG = oc >> 6, rt = (oc >> 4) & 3, ks = (ch >> 5) & 1;
  unsigned l = (oc & 15) | (((ch >> 3) & 3) << 4), e = ch & 7;
  return ((((kc * Mdiv + moG) * 4 + rt) * 2 + ks) * 64 + l) * 8 + e;
}

// ================= prep: pe table + weight conversions =================
__global__ void k_prep(const float* __restrict__ spw, const float* __restrict__ opw,
                       const float* __restrict__ postw,
                       float* __restrict__ peT, unsigned short* __restrict__ pwqs,
                       unsigned short* __restrict__ wop, unsigned short* __restrict__ wc) {
  unsigned id = blockIdx.x * 256u + threadIdx.x;
  if (id < 16384u) {
    int p = id >> 7, j = id & 127;
    float div = expf(-9.210340371976184f * (float)(j & ~1) * (1.0f / 128.0f));
    float ang = (float)p * div;
    peT[id] = (j & 1) ? cosf(ang) : sinf(ang);
    return;
  }
  unsigned i = id - 16384u;
  if (i >= 1310720u) return;
  if (i < 65536u) {
    unsigned oc = i >> 8, ch = i & 255u;
    pwqs[pack_idx(oc + 256u, ch, 8u)] = f2b(spw[i]);
  } else if (i < 131072u) {
    wop[i - 65536u] = f2b(opw[i - 65536u]);
  } else {
    unsigned r = i - 131072u;
    unsigned e = r & 7u, l = (r >> 3) & 63u, rt = (r >> 9) & 3u;
    unsigned idx3 = r >> 11;
    unsigned tap = idx3 % 9u, q = idx3 / 9u;
    unsigned ocb = q & 3u, cc = q >> 2;
    unsigned oc = ocb * 64u + rt * 16u + (l & 15u);
    unsigned ic = cc * 32u + (l >> 4) * 8u + e;
    wc[r] = f2b(postw[(oc * 512u + ic) * 9u + tap]);
  }
}

// ================= fold: combined weights (packed) + PE tables =================
__global__ void k_fold(const float* __restrict__ qpw, const float* __restrict__ kpw,
                       const float* __restrict__ vpw, const float* __restrict__ inw,
                       const float* __restrict__ inb, const float* __restrict__ peT,
                       unsigned short* __restrict__ pwqs, unsigned short* __restrict__ pwk,
                       unsigned short* __restrict__ pwv, float* __restrict__ tb) {
  __shared__ float wrow[256];
  const int tid = threadIdx.x, bid = blockIdx.x;
  if (bid < 768) {
    int m = bid >> 8;                 // 0 q, 1 k, 2 v
    int e2 = bid & 255;
    wrow[tid] = inw[(m * 256 + e2) * 256 + tid];
    __syncthreads();
    if (m == 1) {
      float a0 = 0.f, a1 = 0.f;
      for (int e = 0; e < 256; ++e) {
        float s = wrow[e];
        a0 = fmaf(s, kpw[e * 512 + tid], a0);
        a1 = fmaf(s, kpw[e * 512 + 256 + tid], a1);
      }
      pwk[pack_idx(e2, tid, 4u)] = f2b(a0);
      pwk[pack_idx(e2, tid + 256, 4u)] = f2b(a1);
    } else {
      const float* pw = (m == 0) ? qpw : vpw;
      float a0 = 0.f;
      for (int e = 0; e < 256; ++e) a0 = fmaf(wrow[e], pw[e * 256 + tid], a0);
      if (m == 0) pwqs[pack_idx(e2, tid, 8u)] = f2b(a0);
      else        pwv[pack_idx(e2, tid, 4u)] = f2b(a0);
    }
  } else {
    int r = bid - 768;
    int t = r >> 7, p = r & 127;      // t: 0 Aq,1 Bq,2 Ak,3 Bk,4 Av,5 Bv
    if (tid < 128) wrow[tid] = peT[p * 128 + tid];
    __syncthreads();
    int woff = (t >> 1) * 256, joff = (t & 1) * 128;
    float acc = (t & 1) ? 0.f : inb[woff + tid];
    const float* wr = inw + (size_t)(woff + tid) * 256 + joff;
    for (int j = 0; j < 128; ++j) acc = fmaf(wrow[j], wr[j], acc);
    tb[t * 32768 + p * 256 + tid] = acc;
  }
}

// ================= shared GEMM (k_wattn): OUT[e][tok] += W[e][c] * X[tok][c] ===========
__device__ __forceinline__ void gemm4x4(f32x4 acc[4][4], const unsigned short* __restrict__ wA,
                                        int Kw, int kw0, const unsigned short* sB, int strideB,
                                        int nK, int wid, int lane) {
  const int rA = lane & 15;
  const int kq = (lane >> 4) << 3;
  for (int ks = 0; ks < nK; ks += 32) {
    bf16x8 a[4];
#pragma unroll
    for (int rt = 0; rt < 4; ++rt)
      a[rt] = *reinterpret_cast<const bf16x8*>(wA + (wid * 64 + rt * 16 + rA) * Kw + kw0 + ks + kq);
#pragma unroll
    for (int ct = 0; ct < 4; ++ct) {
      bf16x8 bb = rd8(sB, ct * 16 + rA, strideB, ks + kq);
#pragma unroll
      for (int rt = 0; rt < 4; ++rt) acc[rt][ct] = MFMA16(a[rt], bb, acc[rt][ct]);
    }
  }
}

// y_t layout: [b][cc=ch/32][h][w][ch%32]
__device__ __forceinline__ void epi_global(unsigned short* __restrict__ y_t, const f32x4 acc[4][4],
                                           const float* __restrict__ bias, int chOff,
                                           int b, int h0, int w0, int wid, int lane) {
#pragma unroll
  for (int rt = 0; rt < 4; ++rt) {
    int e0 = wid * 64 + rt * 16 + ((lane >> 4) << 2);
    float4 bs = bias ? *reinterpret_cast<const float4*>(bias + e0) : make_float4(0.f, 0.f, 0.f, 0.f);
    int ch = chOff + e0;
#pragma unroll
    for (int ct = 0; ct < 4; ++ct) {
      int tok = ct * 16 + (lane & 15);
      int r = tok >> 3, cpx = tok & 7;
      long gy = ((((long)(b * 16 + (ch >> 5)) * 128 + (h0 + r)) * 128 + (w0 + cpx)) << 5) + (ch & 31);
      ushort4 pk;
      pk.x = f2b(acc[rt][ct][0] + bs.x);
      pk.y = f2b(acc[rt][ct][1] + bs.y);
      pk.z = f2b(acc[rt][ct][2] + bs.z);
      pk.w = f2b(acc[rt][ct][3] + bs.w);
      *reinterpret_cast<ushort4*>(y_t + gy) = pk;
    }
  }
}

// ================= projections v3: 512-thr, 32oc-waves, 2 blocks/CU =================
// block = 512 thr / 8 waves (2 win x 4 og); tile = 128 tok (8h x 16w) x 128 oc
// 8 unit-blocks per token tile: q0,q1,s0,s1,k0,k1,v0,v1; grid 8192, XCD-grouped
__launch_bounds__(512, 4)
__global__ void k_proj(const float* __restrict__ x5, const float* __restrict__ d1,
                       const float* __restrict__ d2,
                       const unsigned short* __restrict__ pwqs, const unsigned short* __restrict__ pwk,
                       const unsigned short* __restrict__ pwv, const float* __restrict__ tb,
                       unsigned short* __restrict__ qh, unsigned short* __restrict__ kh,
                       unsigned short* __restrict__ vt, unsigned short* __restrict__ y_t) {
  __shared__ unsigned short sB2[2][8192];   // [128 tok][64 ch] swizzled, dbuf
  const int tid = threadIdx.x, l = tid & 63, wv = tid >> 6;
  const int l15 = l & 15, gq = l >> 4;
  const int braw = blockIdx.x;
  const int bid = (braw & 7) * 1024 + (braw >> 3);     // XCD-grouped
  const int u = bid & 7, tile = bid >> 3;
  const int wt = tile & 7, hs = (tile >> 3) & 15, b = tile >> 7;
  const int h0 = hs * 8, w0 = wt * 16;
  const int win = wv & 1, og = wv >> 1;                // 2 win x 4 og waves

  const float* src; const unsigned short* wf; int Cin, nkc, Mdiv, moGb, mode;
  switch (u) {
    case 0:  src = d1; wf = pwqs; Cin = 256; nkc = 4; Mdiv = 8; moGb = 0; mode = 0; break;
    case 1:  src = d1; wf = pwqs; Cin = 256; nkc = 4; Mdiv = 8; moGb = 2; mode = 0; break;
    case 2:  src = d1; wf = pwqs; Cin = 256; nkc = 4; Mdiv = 8; moGb = 4; mode = 1; break;
    case 3:  src = d1; wf = pwqs; Cin = 256; nkc = 4; Mdiv = 8; moGb = 6; mode = 1; break;
    case 4:  src = x5; wf = pwk;  Cin = 512; nkc = 8; Mdiv = 4; moGb = 0; mode = 2; break;
    case 5:  src = x5; wf = pwk;  Cin = 512; nkc = 8; Mdiv = 4; moGb = 2; mode = 2; break;
    case 6:  src = d2; wf = pwv;  Cin = 256; nkc = 4; Mdiv = 4; moGb = 0; mode = 3; break;
    default: src = d2; wf = pwv;  Cin = 256; nkc = 4; Mdiv = 4; moGb = 2; mode = 3; break;
  }
  const int moG = moGb + (og >> 1), rtb = (og & 1) * 2;

  // staging map: tid -> (colq 0..3, hh 0..7, ch0 0..15); 4 float4 per thread per kc
  const int colq = tid & 3, hh = (tid >> 2) & 7, ch0 = tid >> 5;
  const long srcb = ((long)(b * Cin) << 14) + (long)(h0 + hh) * 128 + w0 + colq * 4;

  // B-frag LDS short-offset bases (per ct); swizzle s = (tok ^ tok>>2) & 7
  int bOff[4];
#pragma unroll
  for (int ct = 0; ct < 4; ++ct) {
    int tok = win * 64 + ct * 16 + l15;
    int s = (tok ^ (tok >> 2)) & 7;
    bOff[ct] = (tok << 6) + ((gq ^ (s & 3)) << 3) + ((s >> 2) << 5);
  }

  const f32x4 vz = {0.f, 0.f, 0.f, 0.f};
  f32x4 acc[2][4];
#pragma unroll
  for (int rt = 0; rt < 2; ++rt)
#pragma unroll
    for (int ct = 0; ct < 4; ++ct) acc[rt][ct] = vz;

  float4 pv[4];
  auto stage = [&](int kc) {
#pragma unroll
    for (int i = 0; i < 4; ++i)
      pv[i] = *reinterpret_cast<const float4*>(src + srcb + ((long)(kc * 64 + i * 16 + ch0) << 14));
  };
  auto wrt = [&](unsigned short* buf) {
#pragma unroll
    for (int i = 0; i < 4; ++i) {
      int c7b = i * 2 + (ch0 >> 3), pos = ch0 & 7;
      const float* f = reinterpret_cast<const float*>(&pv[i]);
#pragma unroll
      for (int e = 0; e < 4; ++e) {
        int wloc = colq * 4 + e;
        int tok = (wloc >> 3) * 64 + hh * 8 + (wloc & 7);
        int s = (tok ^ (tok >> 2)) & 7;
        buf[(tok << 6) + ((c7b ^ s) << 3) + pos] = f2b(f[e]);
      }
    }
  };

  stage(0);
  wrt(sB2[0]);
  __syncthreads();

#pragma unroll 1
  for (int kc = 0; kc < nkc; ++kc) {
    const unsigned short* buf = sB2[kc & 1];
    if (kc + 1 < nkc) stage(kc + 1);                   // issue early (T14)
    const unsigned short* pa = wf + (((kc * Mdiv + moG) << 12) | (l << 3));
#pragma unroll
    for (int ksi = 0; ksi < 2; ++ksi) {
      bf16x8 a0 = *reinterpret_cast<const bf16x8*>(pa + (((rtb + 0) * 2 + ksi) << 9));
      bf16x8 a1 = *reinterpret_cast<const bf16x8*>(pa + (((rtb + 1) * 2 + ksi) << 9));
#pragma unroll
      for (int ct = 0; ct < 4; ++ct) {
        bf16x8 bb = *reinterpret_cast<const bf16x8*>(buf + (bOff[ct] ^ (ksi << 5)));
        acc[0][ct] = MFMA16(a0, bb, acc[0][ct]);
        acc[1][ct] = MFMA16(a1, bb, acc[1][ct]);
      }
    }
    if (kc + 1 < nkc) wrt(sB2[(kc + 1) & 1]);          // write late (T14)
    __syncthreads();
  }

  // ---- epilogues ----
  const int win_g = ((b * 16 + hs) << 4) + wt * 2 + win;
  if (mode == 0 || mode == 2) {
    const float* At = tb + (mode == 0 ? 0 : 65536);
    const float* Bt = tb + (mode == 0 ? 32768 : 98304);
    unsigned short* dst = (mode == 0 ? qh : kh) + ((size_t)win_g << 14);
#pragma unroll
    for (int rt = 0; rt < 2; ++rt) {
      int oc = moG * 64 + (rtb + rt) * 16 + gq * 4;
#pragma unroll
      for (int ct = 0; ct < 4; ++ct) {
        int wtok = ct * 16 + l15;
        int h = h0 + (wtok >> 3), wgl = w0 + win * 8 + (wtok & 7);
        float4 av = *reinterpret_cast<const float4*>(At + h * 256 + oc);
        float4 bv = *reinterpret_cast<const float4*>(Bt + wgl * 256 + oc);
        ushort4 pk;
        pk.x = f2b(acc[rt][ct][0] + av.x + bv.x);
        pk.y = f2b(acc[rt][ct][1] + av.y + bv.y);
        pk.z = f2b(acc[rt][ct][2] + av.z + bv.z);
        pk.w = f2b(acc[rt][ct][3] + av.w + bv.w);
        *reinterpret_cast<ushort4*>(dst + ((oc >> 5) << 11) + (wtok << 5) + (oc & 31)) = pk;
      }
    }
  } else if (mode == 1) {
#pragma unroll
    for (int rt = 0; rt < 2; ++rt) {
      int ch = moG * 64 + (rtb + rt) * 16 + gq * 4;   // 256..511
      int cc = ch >> 5;
#pragma unroll
      for (int ct = 0; ct < 4; ++ct) {
        int wtok = ct * 16 + l15;
        int h = h0 + (wtok >> 3), wgl = w0 + win * 8 + (wtok & 7);
        long gy = ((((long)(b * 16 + cc) * 128 + h) * 128 + wgl) << 5) + (ch & 31);
        ushort4 pk;
        pk.x = f2b(acc[rt][ct][0]);
        pk.y = f2b(acc[rt][ct][1]);
        pk.z = f2b(acc[rt][ct][2]);
        pk.w = f2b(acc[rt][ct][3]);
        *reinterpret_cast<ushort4*>(y_t + gy) = pk;
      }
    }
  } else {
    const float* At = tb + 131072;
    const float* Bt = tb + 163840;
    unsigned short* dst = vt + ((size_t)win_g << 14);
#pragma unroll
    for (int rt = 0; rt < 2; ++rt) {
      int oc = moG * 64 + (rtb + rt) * 16 + gq * 4;
      int hd = oc >> 5, chb = oc & 31;
#pragma unroll
      for (int ct = 0; ct < 4; ++ct) {
        int wtok = ct * 16 + l15;
        int h = h0 + (wtok >> 3), wgl = w0 + win * 8 + (wtok & 7);
        float4 av = *reinterpret_cast<const float4*>(At + h * 256 + oc);
        float4 bv = *reinterpret_cast<const float4*>(Bt + wgl * 256 + oc);
        const float* avf = reinterpret_cast<const float*>(&av);
        const float* bvf = reinterpret_cast<const float*>(&bv);
#pragma unroll
        for (int j = 0; j < 4; ++j)
          dst[(hd << 11) + (chb + j) * 64 + wtok] = f2b(acc[rt][ct][j] + avf[j] + bvf[j]);
      }
    }
  }
}

// ================= window attention + out-proj (unchanged) =================
__launch_bounds__(256, 3)
__global__ void k_wattn(const unsigned short* __restrict__ qh, const unsigned short* __restrict__ kh,
                        const unsigned short* __restrict__ vt, const unsigned short* __restrict__ wop,
                        const float* __restrict__ out_b, unsigned short* __restrict__ y_t) {
  __shared__ unsigned short Pb[4096];
  __shared__ unsigned short bufO[16384];
  const int tid = threadIdx.x, lane = tid & 63, wid = tid >> 6;
  const int gq = lane >> 4, l15 = lane & 15, kq = gq << 3;
  const int bid = blockIdx.x;
  const int win = ((bid & 7) << 8) | (bid >> 3);
  const int b = win >> 8, wh = (win >> 4) & 15, ww = win & 15;
  const int h0 = wh * 8, w0 = ww * 8;

  const unsigned short* qw = qh + ((size_t)win << 14);
  const unsigned short* kw = kh + ((size_t)win << 14);
  const unsigned short* vw = vt + ((size_t)win << 14);

  const f32x4 vz = {0.f, 0.f, 0.f, 0.f};
  const float scl = 0.17677669529663687f;
  f32x4 o0[8], o1[8];
#pragma unroll
  for (int h = 0; h < 8; ++h) { o0[h] = vz; o1[h] = vz; }

#pragma unroll
  for (int hd = 0; hd < 8; ++hd) {
    const unsigned short* qb = qw + (hd << 11);
    const unsigned short* kb = kw + (hd << 11);
    const unsigned short* vb = vw + (hd << 11);
    bf16x8 aq = *reinterpret_cast<const bf16x8*>(qb + ((wid * 16 + l15) << 5) + kq);
    f32x4 sv[4];
#pragma unroll
    for (int ct = 0; ct < 4; ++ct) {
      bf16x8 bk = *reinterpret_cast<const bf16x8*>(kb + ((ct * 16 + l15) << 5) + kq);
      sv[ct] = MFMA16(aq, bk, vz);
    }
    float pr[4][4];
#pragma unroll
    for (int j = 0; j < 4; ++j) {
      float mx = fmaxf(fmaxf(sv[0][j], sv[1][j]), fmaxf(sv[2][j], sv[3][j])) * scl;
#pragma unroll
      for (int m = 8; m >= 1; m >>= 1) mx = fmaxf(mx, __shfl_xor(mx, m));
      float sum = 0.f;
#pragma unroll
      for (int ct = 0; ct < 4; ++ct) {
        float p = __expf(sv[ct][j] * scl - mx);
        pr[ct][j] = p;
        sum += p;
      }
#pragma unroll
      for (int m = 8; m >= 1; m >>= 1) sum += __shfl_xor(sum, m);
      float inv = 1.f / sum;
#pragma unroll
      for (int ct = 0; ct < 4; ++ct) pr[ct][j] *= inv;
    }
#pragma unroll
    for (int ct = 0; ct < 4; ++ct)
#pragma unroll
      for (int j = 0; j < 4; ++j) {
        int q = wid * 16 + gq * 4 + j;
        int kt = ct * 16 + l15;
        Pb[q * 64 + (kt ^ ((q & 7) << 3))] = f2b(pr[ct][j]);
      }
#pragma unroll
    for (int ks = 0; ks < 64; ks += 32) {
      bf16x8 bp = rd8(Pb, wid * 16 + l15, 64, ks + kq);
      bf16x8 a0 = *reinterpret_cast<const bf16x8*>(vb + (l15 << 6) + ks + kq);
      bf16x8 a1 = *reinterpret_cast<const bf16x8*>(vb + ((16 + l15) << 6) + ks + kq);
      o0[hd] = MFMA16(a0, bp, o0[hd]);
      o1[hd] = MFMA16(a1, bp, o1[hd]);
    }
  }

  {
    int tok = wid * 16 + l15;
    int sw = (tok & 7) << 3;
#pragma unroll
    for (int hd = 0; hd < 8; ++hd)
#pragma unroll
      for (int rt = 0; rt < 2; ++rt) {
        f32x4 ov = rt ? o1[hd] : o0[hd];
        int ch0 = hd * 32 + rt * 16 + gq * 4;
        ushort4 pk;
        pk.x = f2b(ov[0]); pk.y = f2b(ov[1]); pk.z = f2b(ov[2]); pk.w = f2b(ov[3]);
        *reinterpret_cast<ushort4*>(&bufO[tok * 256 + (ch0 ^ sw)]) = pk;
      }
  }
  __syncthreads();

  f32x4 accA[4][4];
#pragma unroll
  for (int i = 0; i < 4; ++i)
#pragma unroll
    for (int j = 0; j < 4; ++j) accA[i][j] = vz;
  gemm4x4(accA, wop, 256, 0, bufO, 256, 256, wid, lane);
  epi_global(y_t, accA, out_b, 0, b, h0, w0, wid, lane);
}

// ================= conv 3x3 (512->256) implicit GEMM (unchanged) =================
__device__ __forceinline__ void patch_load(const unsigned short* __restrict__ y_t,
                                           int b, int cc, int h0, int w0, int tid, uint4* pv) {
#pragma unroll
  for (int k = 0; k < 5; ++k) {
    int s = tid + (k << 9);
    uint4 v = make_uint4(0u, 0u, 0u, 0u);
    if (s < 2448) {
      int pr = (s * 482) >> 16;
      int rem = s - pr * 136;
      int pcpx = rem >> 2, g = rem & 3;
      int hh = h0 + pr - 1, wp = w0 + pcpx - 1;
      if ((unsigned)hh < 128u && (unsigned)wp < 128u)
        v = *reinterpret_cast<const uint4*>(
            y_t + ((((long)(b * 16 + cc) * 128 + hh) * 128 + wp) << 5) + (g << 3));
    }
    pv[k] = v;
  }
}

__device__ __forceinline__ void patch_store(unsigned short* buf, int tid, const uint4* pv) {
#pragma unroll
  for (int k = 0; k < 5; ++k) {
    int s = tid + (k << 9);
    if (s < 2448) {
      int pr = (s * 482) >> 16;
      int rem = s - pr * 136;
      int pcpx = rem >> 2, g = rem & 3;
      int pidx = pr * 34 + pcpx;
      *reinterpret_cast<uint4*>(buf + (pidx << 5) + ((g ^ ((pidx >> 1) & 3)) << 3)) = pv[k];
    }
  }
}

__device__ __forceinline__ void stage_A(const unsigned short* __restrict__ wA, int cc, int ocb,
                                        unsigned short* dstBase, int tid) {
  const unsigned short* src = wA + (size_t)(cc * 4 + ocb) * 18432 + tid * 8;
  unsigned short* dst = dstBase + tid * 8;
#pragma unroll
  for (int k = 0; k < 4; ++k) {
    __builtin_amdgcn_global_load_lds(
        (const __attribute__((address_space(1))) unsigned int*)(src + k * 4096),
        (__attribute__((address_space(3))) unsigned int*)(dst + k * 4096), 16, 0, 0);
  }
  if (tid < 256)
    __builtin_amdgcn_global_load_lds(
        (const __attribute__((address_space(1))) unsigned int*)(src + 16384),
        (__attribute__((address_space(3))) unsigned int*)(dst + 16384), 16, 0, 0);
}

__launch_bounds__(512, 2)
__global__ void k_conv(const unsigned short* __restrict__ y_t, const unsigned short* __restrict__ wc,
                       float* __restrict__ out) {
  extern __shared__ unsigned short cs[];
  unsigned short* Pb0 = cs;
  unsigned short* Pb1 = cs + 19584;
  unsigned short* Ab0 = cs + 39168;
  unsigned short* Ab1 = cs + 57600;

  const int tid = threadIdx.x, lane = tid & 63, pxg = tid >> 6;
  const int gq = lane >> 4, l15 = lane & 15;
  const int bi = ((int)blockIdx.x & 7) * 128 + ((int)blockIdx.x >> 3);
  const int ocb = bi & 3, wb = (bi >> 2) & 3, hb = (bi >> 4) & 7, b = bi >> 7;
  const int h0 = hb * 16, w0 = wb * 32;

  const f32x4 vz = {0.f, 0.f, 0.f, 0.f};
  f32x4 acc[4][4];
#pragma unroll
  for (int rt = 0; rt < 4; ++rt)
#pragma unroll
    for (int ct = 0; ct < 4; ++ct) acc[rt][ct] = vz;

  uint4 pv[5];
  patch_load(y_t, b, 0, h0, w0, tid, pv);
  stage_A(wc, 0, ocb, Ab0, tid);
  patch_store(Pb0, tid, pv);
  __syncthreads();

#pragma unroll 1
  for (int cc = 0; cc < 16; ++cc) {
    const unsigned short* pb = (cc & 1) ? Pb1 : Pb0;
    const unsigned short* pa = (cc & 1) ? Ab1 : Ab0;
    if (cc < 15) {
      patch_load(y_t, b, cc + 1, h0, w0, tid, pv);
      stage_A(wc, cc + 1, ocb, (cc & 1) ? Ab0 : Ab1, tid);
    }

#pragma unroll
    for (int kx = 0; kx < 3; ++kx) {
      bf16x8 bfr[4][2];
#pragma unroll
      for (int r = 0; r < 4; ++r)
#pragma unroll
        for (int ws = 0; ws < 2; ++ws) {
          int pidx = (pxg * 2 + r) * 34 + ws * 16 + l15 + kx;
          bfr[r][ws] = *reinterpret_cast<const bf16x8*>(
              pb + (pidx << 5) + ((gq ^ ((pidx >> 1) & 3)) << 3));
        }
      bf16x8 afr[3][4];
#pragma unroll
      for (int ky = 0; ky < 3; ++ky)
#pragma unroll
        for (int rt = 0; rt < 4; ++rt)
          afr[ky][rt] = *reinterpret_cast<const bf16x8*>(
              pa + (((ky * 3 + kx) * 4 + rt) << 9) + lane * 8);
#pragma unroll
      for (int ky = 0; ky < 3; ++ky)
#pragma unroll
        for (int ct = 0; ct < 4; ++ct) {
          int r = (ct >> 1) + ky, ws = ct & 1;
#pragma unroll
          for (int rt = 0; rt < 4; ++rt)
            acc[rt][ct] = MFMA16(afr[ky][rt], bfr[r][ws], acc[rt][ct]);
        }
    }

    if (cc < 15) patch_store((cc & 1) ? Pb0 : Pb1, tid, pv);
    __syncthreads();
  }

#pragma unroll
  for (int rt = 0; rt < 4; ++rt) {
    int oc0 = ocb * 64 + rt * 16 + gq * 4;
#pragma unroll
    for (int ct = 0; ct < 4; ++ct) {
      int hh = h0 + pxg * 2 + (ct >> 1), wp = w0 + ((ct & 1) << 4) + l15;
      long base = (((long)(b * 256 + oc0)) * 128 + hh) * 128 + wp;
#pragma unroll
      for (int j = 0; j < 4; ++j) out[base + (long)j * 16384] = acc[rt][ct][j];
    }
  }
}

// ================= BN stats / finalize / apply =================
__global__ void k_stats(const float* __restrict__ out, float* __restrict__ sums) {
  __shared__ float s1[256], s2[256];
  int c = blockIdx.x, tid = threadIdx.x;
  float a1 = 0.f, a2 = 0.f;
  for (int bb = 0; bb < 8; ++bb) {
    const float4* p = reinterpret_cast<const float4*>(out + ((long)(bb * 256 + c)) * 16384);
    for (int i = tid; i < 4096; i += 256) {
      float4 v = p[i];
      a1 += v.x + v.y + v.z + v.w;
      a2 += v.x * v.x + v.y * v.y + v.z * v.z + v.w * v.w;
    }
  }
  s1[tid] = a1; s2[tid] = a2;
  __syncthreads();
  for (int s = 128; s > 0; s >>= 1) {
    if (tid < s) { s1[tid] += s1[tid + s]; s2[tid] += s2[tid + s]; }
    __syncthreads();
  }
  if (tid == 0) { sums[c] = s1[0]; sums[256 + c] = s2[0]; }
}

__global__ void k_final(const float* __restrict__ sums, const float* __restrict__ gamma,
                        const float* __restrict__ beta, float* __restrict__ sc) {
  int c = threadIdx.x;
  float mean = sums[c] * (1.f / 131072.f);
  float var = sums[256 + c] * (1.f / 131072.f) - mean * mean;
  float s = gamma[c] * rsqrtf(var + 1e-5f);
  sc[c] = s;
  sc[256 + c] = beta[c] - mean * s;
}

__global__ void k_apply(float* __restrict__ out, const float* __restrict__ sc) {
  const long n4 = 33554432 / 4;
  for (long i4 = (long)blockIdx.x * 256 + threadIdx.x; i4 < n4; i4 += (long)gridDim.x * 256) {
    float4 v = reinterpret_cast<float4*>(out)[i4];
    int c = (int)((i4 >> 12) & 255);
    float s = sc[c], sh = sc[256 + c];
    v.x = fmaxf(v.x * s + sh, 0.f);
    v.y = fmaxf(v.y * s + sh, 0.f);
    v.z = fmaxf(v.z * s + sh, 0.f);
    v.w = fmaxf(v.w * s + sh, 0.f);
    reinterpret_cast<float4*>(out)[i4] = v;
  }
}

// ================= launch =================
extern "C" void kernel_launch(void* const* d_in, const int* in_sizes, int n_in,
                              void* d_out, int out_size, void* d_ws, size_t ws_size,
                              hipStream_t stream) {
  const float* x5 = (const float*)d_in[0];
  const float* d1 = (const float*)d_in[1];
  const float* d2 = (const float*)d_in[2];
  const float* kp = (const float*)d_in[3];
  const float* qp = (const float*)d_in[4];
  const float* vp = (const float*)d_in[5];
  const float* spw = (const float*)d_in[6];
  const float* inw = (const float*)d_in[7];
  const float* inb = (const float*)d_in[8];
  const float* opw = (const float*)d_in[9];
  const float* opb = (const float*)d_in[10];
  const float* pw = (const float*)d_in[11];
  const float* gamma = (const float*)d_in[12];
  const float* beta = (const float*)d_in[13];

  if (ws_size < (size_t)WSO_TOTAL) {
    fprintf(stderr, "kernel_launch: ws too small: %zu < %u\n", ws_size, WSO_TOTAL);
    return;
  }

  char* ws = (char*)d_ws;
  float* peT = (float*)(ws + WSO_PE);
  unsigned short* pwqs = (unsigned short*)(ws + WSO_PWQS);
  unsigned short* pwk = (unsigned short*)(ws + WSO_PWK);
  unsigned short* pwv = (unsigned short*)(ws + WSO_PWV);
  unsigned short* w_op = (unsigned short*)(ws + WSO_WOP);
  unsigned short* w_c = (unsigned short*)(ws + WSO_WC);
  float* tb = (float*)(ws + WSO_TB);
  unsigned short* qh = (unsigned short*)(ws + WSO_QH);
  unsigned short* kh = (unsigned short*)(ws + WSO_KH);
  unsigned short* vt = (unsigned short*)(ws + WSO_VT);
  unsigned short* y_t = (unsigned short*)(ws + WSO_YT);
  float* sums = (float*)(ws + WSO_SUMS);
  float* sc = (float*)(ws + WSO_SC);

  hipFuncSetAttribute(reinterpret_cast<const void*>(k_conv),
                      hipFuncAttributeMaxDynamicSharedMemorySize, SMEM_CONV);

  k_prep<<<5184, 256, 0, stream>>>(spw, opw, pw, peT, pwqs, w_op, w_c);
  k_fold<<<1536, 256, 0, stream>>>(qp, kp, vp, inw, inb, peT, pwqs, pwk, pwv, tb);
  k_proj<<<8192, 512, 0, stream>>>(x5, d1, d2, pwqs, pwk, pwv, tb, qh, kh, vt, y_t);
  k_wattn<<<2048, 256, 0, stream>>>(qh, kh, vt, w_op, opb, y_t);
  k_conv<<<1024, 512, SMEM_CONV, stream>>>(y_t, w_c, (float*)d_out);
  k_stats<<<256, 256, 0, stream>>>((const float*)d_out, sums);
  k_final<<<1, 256, 0, stream>>>(sums, gamma, beta, sc);
  k_apply<<<2048, 256, 0, stream>>>((float*)d_out, sc);
}